// Round 1
// baseline (3475.927 us; speedup 1.0000x reference)
//
#include <hip/hip_runtime.h>
#include <cstddef>

#define DD 128
#define TILE_R 128
#define GBLK 512
#define AS_LD 132   // padded LDS stride for A tile (keeps f4 writes 16B-aligned, banks spread)

__device__ __forceinline__ float4 f4add(const float4& a, const float4& b) {
    return make_float4(a.x + b.x, a.y + b.y, a.z + b.z, a.w + b.w);
}
__device__ __forceinline__ float4 f4scale(const float4& a, float s) {
    return make_float4(a.x * s, a.y * s, a.z * s, a.w * s);
}
__device__ __forceinline__ float4 f4relu(const float4& a) {
    return make_float4(fmaxf(a.x, 0.f), fmaxf(a.y, 0.f), fmaxf(a.z, 0.f), fmaxf(a.w, 0.f));
}
__device__ __forceinline__ void f4fma(float a, const float4& b, float4& c) {
    c.x = fmaf(a, b.x, c.x);
    c.y = fmaf(a, b.y, c.y);
    c.z = fmaf(a, b.z, c.z);
    c.w = fmaf(a, b.w, c.w);
}

// ---------------------------------------------------------------------------
// e_out = e  (f4 streaming copy)
__global__ void copy_e_kernel(const float* __restrict__ e, float* __restrict__ eout, int n4) {
    int g = blockIdx.x * blockDim.x + threadIdx.x;
    if (g < n4) {
        reinterpret_cast<float4*>(eout)[g] = reinterpret_cast<const float4*>(e)[g];
    }
}

// ---------------------------------------------------------------------------
// GEMM1: vw = relu(v @ W + b_v) * v_weight ; v_out = v * v_weight * 4
__global__ __launch_bounds__(GBLK, 1)
void gemm_v2e_kernel(const float* __restrict__ v, const float* __restrict__ W,
                     const float* __restrict__ bv, const float* __restrict__ vweight,
                     float* __restrict__ vw, float* __restrict__ vout, int nrows)
{
    __shared__ float Ws[DD * DD];          // 64 KB
    __shared__ float As[TILE_R * AS_LD];   // ~66 KB

    const int t = threadIdx.x;
    const int row0 = blockIdx.x * TILE_R;

    // stage W (16384 floats = 4096 f4, 512 thr x 8)
    #pragma unroll
    for (int i = 0; i < 8; ++i) {
        int p = t + GBLK * i;
        *reinterpret_cast<float4*>(&Ws[p * 4]) = *reinterpret_cast<const float4*>(&W[p * 4]);
    }
    // stage A tile (128 rows x 32 f4)
    #pragma unroll
    for (int i = 0; i < 8; ++i) {
        int p  = t + GBLK * i;
        int r  = p >> 5;
        int c4 = p & 31;
        int gr = row0 + r;
        float4 val = make_float4(0.f, 0.f, 0.f, 0.f);
        if (gr < nrows) val = *reinterpret_cast<const float4*>(&v[(size_t)gr * DD + c4 * 4]);
        *reinterpret_cast<float4*>(&As[r * AS_LD + c4 * 4]) = val;
    }
    __syncthreads();

    const int rg = t >> 4;      // 0..31
    const int cg = t & 15;      // 0..15
    const int r0 = rg * 4;
    const int c0 = cg * 4;
    const int c1 = 64 + cg * 4;

    float4 acc0[4], acc1[4];
    #pragma unroll
    for (int i = 0; i < 4; ++i) {
        acc0[i] = make_float4(0.f, 0.f, 0.f, 0.f);
        acc1[i] = make_float4(0.f, 0.f, 0.f, 0.f);
    }

    #pragma unroll 4
    for (int k = 0; k < DD; ++k) {
        float4 b0 = *reinterpret_cast<const float4*>(&Ws[k * DD + c0]);
        float4 b1 = *reinterpret_cast<const float4*>(&Ws[k * DD + c1]);
        #pragma unroll
        for (int i = 0; i < 4; ++i) {
            float a = As[(r0 + i) * AS_LD + k];
            f4fma(a, b0, acc0[i]);
            f4fma(a, b1, acc1[i]);
        }
    }

    float4 bv0 = *reinterpret_cast<const float4*>(&bv[c0]);
    float4 bv1 = *reinterpret_cast<const float4*>(&bv[c1]);

    #pragma unroll
    for (int i = 0; i < 4; ++i) {
        int gr = row0 + r0 + i;
        if (gr >= nrows) break;
        float wt = vweight[gr];
        float4 o0 = f4scale(f4relu(f4add(acc0[i], bv0)), wt);
        float4 o1 = f4scale(f4relu(f4add(acc1[i], bv1)), wt);
        *reinterpret_cast<float4*>(&vw[(size_t)gr * DD + c0]) = o0;
        *reinterpret_cast<float4*>(&vw[(size_t)gr * DD + c1]) = o1;
        float s = wt * 4.0f;
        float4 a0 = *reinterpret_cast<const float4*>(&As[(r0 + i) * AS_LD + c0]);
        float4 a1 = *reinterpret_cast<const float4*>(&As[(r0 + i) * AS_LD + c1]);
        *reinterpret_cast<float4*>(&vout[(size_t)gr * DD + c0]) = f4scale(a0, s);
        *reinterpret_cast<float4*>(&vout[(size_t)gr * DD + c1]) = f4scale(a1, s);
    }
}

// ---------------------------------------------------------------------------
// GEMM2: finalize e_out (divide by e_reg_sum, write back), ev = relu(e_out @ W + b_e) / 3
__global__ __launch_bounds__(GBLK, 1)
void gemm_e2v_kernel(float* __restrict__ eout, const float* __restrict__ W,
                     const float* __restrict__ be, const float* __restrict__ ers,
                     float* __restrict__ ev, int nrows)
{
    __shared__ float Ws[DD * DD];
    __shared__ float As[TILE_R * AS_LD];

    const int t = threadIdx.x;
    const int row0 = blockIdx.x * TILE_R;

    #pragma unroll
    for (int i = 0; i < 8; ++i) {
        int p = t + GBLK * i;
        *reinterpret_cast<float4*>(&Ws[p * 4]) = *reinterpret_cast<const float4*>(&W[p * 4]);
    }
    // stage E tile with division and write-back of final e_out
    #pragma unroll
    for (int i = 0; i < 8; ++i) {
        int p  = t + GBLK * i;
        int r  = p >> 5;
        int c4 = p & 31;
        int gr = row0 + r;
        float4 val = make_float4(0.f, 0.f, 0.f, 0.f);
        if (gr < nrows) {
            float rs = 1.0f / ers[gr];
            val = *reinterpret_cast<const float4*>(&eout[(size_t)gr * DD + c4 * 4]);
            val = f4scale(val, rs);
            *reinterpret_cast<float4*>(&eout[(size_t)gr * DD + c4 * 4]) = val;
        }
        *reinterpret_cast<float4*>(&As[r * AS_LD + c4 * 4]) = val;
    }
    __syncthreads();

    const int rg = t >> 4;
    const int cg = t & 15;
    const int r0 = rg * 4;
    const int c0 = cg * 4;
    const int c1 = 64 + cg * 4;

    float4 acc0[4], acc1[4];
    #pragma unroll
    for (int i = 0; i < 4; ++i) {
        acc0[i] = make_float4(0.f, 0.f, 0.f, 0.f);
        acc1[i] = make_float4(0.f, 0.f, 0.f, 0.f);
    }

    #pragma unroll 4
    for (int k = 0; k < DD; ++k) {
        float4 b0 = *reinterpret_cast<const float4*>(&Ws[k * DD + c0]);
        float4 b1 = *reinterpret_cast<const float4*>(&Ws[k * DD + c1]);
        #pragma unroll
        for (int i = 0; i < 4; ++i) {
            float a = As[(r0 + i) * AS_LD + k];
            f4fma(a, b0, acc0[i]);
            f4fma(a, b1, acc1[i]);
        }
    }

    float4 be0 = *reinterpret_cast<const float4*>(&be[c0]);
    float4 be1 = *reinterpret_cast<const float4*>(&be[c1]);
    const float third = 1.0f / 3.0f;

    #pragma unroll
    for (int i = 0; i < 4; ++i) {
        int gr = row0 + r0 + i;
        if (gr >= nrows) break;
        float4 o0 = f4scale(f4relu(f4add(acc0[i], be0)), third);
        float4 o1 = f4scale(f4relu(f4add(acc1[i], be1)), third);
        *reinterpret_cast<float4*>(&ev[(size_t)gr * DD + c0]) = o0;
        *reinterpret_cast<float4*>(&ev[(size_t)gr * DD + c1]) = o1;
    }
}

// ---------------------------------------------------------------------------
// scatter: dst[didx[m]] += src[sidx[m]] * w[m]   (32 lanes per incidence, f4 + 4 atomics)
__global__ void scatter_kernel(const float* __restrict__ src, const int* __restrict__ sidx,
                               const int* __restrict__ didx, const float* __restrict__ w,
                               float* __restrict__ dst, int M)
{
    int g = blockIdx.x * blockDim.x + threadIdx.x;
    int m = g >> 5;
    if (m >= M) return;
    int lane = g & 31;
    int sr = sidx[m];
    int dr = didx[m];
    float wm = w[m];
    float4 x = *reinterpret_cast<const float4*>(&src[(size_t)sr * DD + lane * 4]);
    float* d = &dst[(size_t)dr * DD + lane * 4];
    unsafeAtomicAdd(d + 0, x.x * wm);
    unsafeAtomicAdd(d + 1, x.y * wm);
    unsafeAtomicAdd(d + 2, x.z * wm);
    unsafeAtomicAdd(d + 3, x.w * wm);
}

// ---------------------------------------------------------------------------
// v_out /= v_reg_sum (per row)
__global__ void div_v_kernel(float* __restrict__ vout, const float* __restrict__ vrs, int n4) {
    int g = blockIdx.x * blockDim.x + threadIdx.x;
    if (g >= n4) return;
    int row = g >> 5;                       // 32 f4 per row
    float rs = 1.0f / vrs[row];
    float4 x = reinterpret_cast<float4*>(vout)[g];
    reinterpret_cast<float4*>(vout)[g] = f4scale(x, rs);
}

// ---------------------------------------------------------------------------
extern "C" void kernel_launch(void* const* d_in, const int* in_sizes, int n_in,
                              void* d_out, int out_size, void* d_ws, size_t ws_size,
                              hipStream_t stream)
{
    const float* v       = (const float*)d_in[0];
    const float* e       = (const float*)d_in[1];
    const int*   vidx    = (const int*)d_in[2];
    const int*   eidx    = (const int*)d_in[3];
    const float* vrw     = (const float*)d_in[4];   // v_reg_weight [M]
    const float* erw     = (const float*)d_in[5];   // e_reg_weight [M]
    const float* vrs     = (const float*)d_in[6];   // v_reg_sum [N]
    const float* ers     = (const float*)d_in[7];   // e_reg_sum [E]
    const float* Wv2e    = (const float*)d_in[8];
    const float* We2v    = (const float*)d_in[9];
    const float* bv      = (const float*)d_in[10];
    const float* be      = (const float*)d_in[11];
    const float* vweight = (const float*)d_in[12];

    const int N = in_sizes[0] / DD;
    const int E = in_sizes[1] / DD;
    const int M = in_sizes[2];

    float* vout = (float*)d_out;
    float* eout = vout + (size_t)N * DD;
    float* vw   = (float*)d_ws;                       // [N, 128]
    float* ev   = vw + (size_t)N * DD;                // [E, 128]

    // 1. e_out = e
    {
        int n4 = E * DD / 4;
        copy_e_kernel<<<(n4 + 255) / 256, 256, 0, stream>>>(e, eout, n4);
    }
    // 2. vw = relu(v@W+b)*vweight ; v_out = v*vweight*4
    gemm_v2e_kernel<<<(N + TILE_R - 1) / TILE_R, GBLK, 0, stream>>>(v, Wv2e, bv, vweight, vw, vout, N);
    // 3. e_out += scatter(vw[vidx] * v_reg_weight) by eidx
    {
        long long threads = (long long)M * 32;
        int blocks = (int)((threads + 255) / 256);
        scatter_kernel<<<blocks, 256, 0, stream>>>(vw, vidx, eidx, vrw, eout, M);
    }
    // 4. e_out /= e_reg_sum (write back); ev = relu(e_out@W+b)/3
    gemm_e2v_kernel<<<(E + TILE_R - 1) / TILE_R, GBLK, 0, stream>>>(eout, We2v, be, ers, ev, E);
    // 5. v_out += scatter(ev[eidx] * e_reg_weight) by vidx
    {
        long long threads = (long long)M * 32;
        int blocks = (int)((threads + 255) / 256);
        scatter_kernel<<<blocks, 256, 0, stream>>>(ev, eidx, vidx, erw, vout, M);
    }
    // 6. v_out /= v_reg_sum
    {
        int n4 = N * DD / 4;
        div_v_kernel<<<(n4 + 255) / 256, 256, 0, stream>>>(vout, vrs, n4);
    }
}

// Round 2
// 799.730 us; speedup vs baseline: 4.3464x; 4.3464x over previous
//
#include <hip/hip_runtime.h>
#include <cstddef>

#define DD 128
#define TILE_R 128
#define GBLK 512
#define AS_LD 132

__device__ __forceinline__ float4 f4add(const float4& a, const float4& b) {
    return make_float4(a.x + b.x, a.y + b.y, a.z + b.z, a.w + b.w);
}
__device__ __forceinline__ float4 f4scale(const float4& a, float s) {
    return make_float4(a.x * s, a.y * s, a.z * s, a.w * s);
}
__device__ __forceinline__ float4 f4relu(const float4& a) {
    return make_float4(fmaxf(a.x, 0.f), fmaxf(a.y, 0.f), fmaxf(a.z, 0.f), fmaxf(a.w, 0.f));
}
__device__ __forceinline__ void f4fma(float a, const float4& b, float4& c) {
    c.x = fmaf(a, b.x, c.x);
    c.y = fmaf(a, b.y, c.y);
    c.z = fmaf(a, b.z, c.z);
    c.w = fmaf(a, b.w, c.w);
}

// ---------------------------------------------------------------------------
// histogram: count incidences per edge and per vertex (one pass over M)
__global__ void hist_kernel(const int* __restrict__ eidx, const int* __restrict__ vidx,
                            int* __restrict__ e_cnt, int* __restrict__ v_cnt, int M)
{
    int m = blockIdx.x * blockDim.x + threadIdx.x;
    if (m >= M) return;
    atomicAdd(&e_cnt[eidx[m]], 1);
    atomicAdd(&v_cnt[vidx[m]], 1);
}

// ---------------------------------------------------------------------------
// exclusive scan of cnt[0..n) -> start[0..n], single workgroup (1024 thr)
__global__ __launch_bounds__(1024)
void scan_kernel(const int* __restrict__ cnt, int* __restrict__ start, int n)
{
    __shared__ int sdata[1024];
    __shared__ int sbase;
    if (threadIdx.x == 0) sbase = 0;
    __syncthreads();
    for (int base = 0; base < n; base += 1024) {
        int i = base + threadIdx.x;
        int v = (i < n) ? cnt[i] : 0;
        sdata[threadIdx.x] = v;
        __syncthreads();
        int x = v;
        for (int off = 1; off < 1024; off <<= 1) {
            int y = (threadIdx.x >= off) ? sdata[threadIdx.x - off] : 0;
            __syncthreads();
            x += y;
            sdata[threadIdx.x] = x;
            __syncthreads();
        }
        if (i < n) start[i] = sbase + x - v;   // exclusive
        __syncthreads();                        // everyone read sbase
        if (threadIdx.x == 1023) sbase += x;    // chunk total
        __syncthreads();
    }
    if (threadIdx.x == 0) start[n] = sbase;
}

// ---------------------------------------------------------------------------
// fill packed CSR payloads: for each incidence, place (src_row, weight) at its
// slot in the destination-sorted order. No perm indirection left for the agg.
__global__ void fill_kernel(const int* __restrict__ eidx, const int* __restrict__ vidx,
                            const float* __restrict__ vrw, const float* __restrict__ erw,
                            const int* __restrict__ e_start, const int* __restrict__ v_start,
                            int* __restrict__ e_cur, int* __restrict__ v_cur,
                            int* __restrict__ e_src, float* __restrict__ e_w,
                            int* __restrict__ v_src, float* __restrict__ v_w, int M)
{
    int m = blockIdx.x * blockDim.x + threadIdx.x;
    if (m >= M) return;
    int ei = eidx[m];
    int vi = vidx[m];
    int p = e_start[ei] + atomicAdd(&e_cur[ei], 1);
    e_src[p] = vi;
    e_w[p]   = vrw[m];
    int q = v_start[vi] + atomicAdd(&v_cur[vi], 1);
    v_src[q] = ei;
    v_w[q]   = erw[m];
}

// ---------------------------------------------------------------------------
// GEMM1: vw = relu(v @ W + b_v) * v_weight
__global__ __launch_bounds__(GBLK, 1)
void gemm_v2e_kernel(const float* __restrict__ v, const float* __restrict__ W,
                     const float* __restrict__ bv, const float* __restrict__ vweight,
                     float* __restrict__ vw, int nrows)
{
    __shared__ float Ws[DD * DD];
    __shared__ float As[TILE_R * AS_LD];

    const int t = threadIdx.x;
    const int row0 = blockIdx.x * TILE_R;

    #pragma unroll
    for (int i = 0; i < 8; ++i) {
        int p = t + GBLK * i;
        *reinterpret_cast<float4*>(&Ws[p * 4]) = *reinterpret_cast<const float4*>(&W[p * 4]);
    }
    #pragma unroll
    for (int i = 0; i < 8; ++i) {
        int p  = t + GBLK * i;
        int r  = p >> 5;
        int c4 = p & 31;
        int gr = row0 + r;
        float4 val = make_float4(0.f, 0.f, 0.f, 0.f);
        if (gr < nrows) val = *reinterpret_cast<const float4*>(&v[(size_t)gr * DD + c4 * 4]);
        *reinterpret_cast<float4*>(&As[r * AS_LD + c4 * 4]) = val;
    }
    __syncthreads();

    const int rg = t >> 4;
    const int cg = t & 15;
    const int r0 = rg * 4;
    const int c0 = cg * 4;
    const int c1 = 64 + cg * 4;

    float4 acc0[4], acc1[4];
    #pragma unroll
    for (int i = 0; i < 4; ++i) {
        acc0[i] = make_float4(0.f, 0.f, 0.f, 0.f);
        acc1[i] = make_float4(0.f, 0.f, 0.f, 0.f);
    }

    #pragma unroll 4
    for (int k = 0; k < DD; ++k) {
        float4 b0 = *reinterpret_cast<const float4*>(&Ws[k * DD + c0]);
        float4 b1 = *reinterpret_cast<const float4*>(&Ws[k * DD + c1]);
        #pragma unroll
        for (int i = 0; i < 4; ++i) {
            float a = As[(r0 + i) * AS_LD + k];
            f4fma(a, b0, acc0[i]);
            f4fma(a, b1, acc1[i]);
        }
    }

    float4 bv0 = *reinterpret_cast<const float4*>(&bv[c0]);
    float4 bv1 = *reinterpret_cast<const float4*>(&bv[c1]);

    #pragma unroll
    for (int i = 0; i < 4; ++i) {
        int gr = row0 + r0 + i;
        if (gr >= nrows) break;
        float wt = vweight[gr];
        float4 o0 = f4scale(f4relu(f4add(acc0[i], bv0)), wt);
        float4 o1 = f4scale(f4relu(f4add(acc1[i], bv1)), wt);
        *reinterpret_cast<float4*>(&vw[(size_t)gr * DD + c0]) = o0;
        *reinterpret_cast<float4*>(&vw[(size_t)gr * DD + c1]) = o1;
    }
}

// ---------------------------------------------------------------------------
// GEMM2: ev = relu(e_out @ W + b_e) / 3   (e_out already final)
__global__ __launch_bounds__(GBLK, 1)
void gemm_e2v_kernel(const float* __restrict__ eout, const float* __restrict__ W,
                     const float* __restrict__ be, float* __restrict__ ev, int nrows)
{
    __shared__ float Ws[DD * DD];
    __shared__ float As[TILE_R * AS_LD];

    const int t = threadIdx.x;
    const int row0 = blockIdx.x * TILE_R;

    #pragma unroll
    for (int i = 0; i < 8; ++i) {
        int p = t + GBLK * i;
        *reinterpret_cast<float4*>(&Ws[p * 4]) = *reinterpret_cast<const float4*>(&W[p * 4]);
    }
    #pragma unroll
    for (int i = 0; i < 8; ++i) {
        int p  = t + GBLK * i;
        int r  = p >> 5;
        int c4 = p & 31;
        int gr = row0 + r;
        float4 val = make_float4(0.f, 0.f, 0.f, 0.f);
        if (gr < nrows) val = *reinterpret_cast<const float4*>(&eout[(size_t)gr * DD + c4 * 4]);
        *reinterpret_cast<float4*>(&As[r * AS_LD + c4 * 4]) = val;
    }
    __syncthreads();

    const int rg = t >> 4;
    const int cg = t & 15;
    const int r0 = rg * 4;
    const int c0 = cg * 4;
    const int c1 = 64 + cg * 4;

    float4 acc0[4], acc1[4];
    #pragma unroll
    for (int i = 0; i < 4; ++i) {
        acc0[i] = make_float4(0.f, 0.f, 0.f, 0.f);
        acc1[i] = make_float4(0.f, 0.f, 0.f, 0.f);
    }

    #pragma unroll 4
    for (int k = 0; k < DD; ++k) {
        float4 b0 = *reinterpret_cast<const float4*>(&Ws[k * DD + c0]);
        float4 b1 = *reinterpret_cast<const float4*>(&Ws[k * DD + c1]);
        #pragma unroll
        for (int i = 0; i < 4; ++i) {
            float a = As[(r0 + i) * AS_LD + k];
            f4fma(a, b0, acc0[i]);
            f4fma(a, b1, acc1[i]);
        }
    }

    float4 be0 = *reinterpret_cast<const float4*>(&be[c0]);
    float4 be1 = *reinterpret_cast<const float4*>(&be[c1]);
    const float third = 1.0f / 3.0f;

    #pragma unroll
    for (int i = 0; i < 4; ++i) {
        int gr = row0 + r0 + i;
        if (gr >= nrows) break;
        float4 o0 = f4scale(f4relu(f4add(acc0[i], be0)), third);
        float4 o1 = f4scale(f4relu(f4add(acc1[i], be1)), third);
        *reinterpret_cast<float4*>(&ev[(size_t)gr * DD + c0]) = o0;
        *reinterpret_cast<float4*>(&ev[(size_t)gr * DD + c1]) = o1;
    }
}

// ---------------------------------------------------------------------------
// e-aggregation: eout[row] = (e[row] + sum_j w_j * vw[src_j]) / ers[row]
// one wave (64 lanes, float2 each) per edge; 4 edges per 256-thread block
__global__ __launch_bounds__(256)
void e_agg_kernel(const float* __restrict__ e, const float* __restrict__ vw,
                  const int* __restrict__ start, const int* __restrict__ src,
                  const float* __restrict__ w, const float* __restrict__ ers,
                  float* __restrict__ eout, int E)
{
    int row = blockIdx.x * 4 + (threadIdx.x >> 6);
    if (row >= E) return;
    int lane = threadIdx.x & 63;
    int s = start[row], t = start[row + 1];
    float2 acc = make_float2(0.f, 0.f);
    for (int j = s; j < t; ++j) {
        int sr = src[j];
        float wm = w[j];
        float2 x = *reinterpret_cast<const float2*>(&vw[(size_t)sr * DD + lane * 2]);
        acc.x = fmaf(x.x, wm, acc.x);
        acc.y = fmaf(x.y, wm, acc.y);
    }
    float rs = 1.0f / ers[row];
    float2 er = *reinterpret_cast<const float2*>(&e[(size_t)row * DD + lane * 2]);
    float2 o = make_float2((er.x + acc.x) * rs, (er.y + acc.y) * rs);
    *reinterpret_cast<float2*>(&eout[(size_t)row * DD + lane * 2]) = o;
}

// ---------------------------------------------------------------------------
// v-aggregation: vout[row] = (v[row]*vweight[row]*4 + sum_j w_j * ev[src_j]) / vrs[row]
__global__ __launch_bounds__(256)
void v_agg_kernel(const float* __restrict__ v, const float* __restrict__ ev,
                  const int* __restrict__ start, const int* __restrict__ src,
                  const float* __restrict__ w, const float* __restrict__ vrs,
                  const float* __restrict__ vweight, float* __restrict__ vout, int N)
{
    int row = blockIdx.x * 4 + (threadIdx.x >> 6);
    if (row >= N) return;
    int lane = threadIdx.x & 63;
    int s = start[row], t = start[row + 1];
    float2 acc = make_float2(0.f, 0.f);
    for (int j = s; j < t; ++j) {
        int sr = src[j];
        float wm = w[j];
        float2 x = *reinterpret_cast<const float2*>(&ev[(size_t)sr * DD + lane * 2]);
        acc.x = fmaf(x.x, wm, acc.x);
        acc.y = fmaf(x.y, wm, acc.y);
    }
    float rs = 1.0f / vrs[row];
    float wt = vweight[row] * 4.0f;
    float2 vr = *reinterpret_cast<const float2*>(&v[(size_t)row * DD + lane * 2]);
    float2 o = make_float2((vr.x * wt + acc.x) * rs, (vr.y * wt + acc.y) * rs);
    *reinterpret_cast<float2*>(&vout[(size_t)row * DD + lane * 2]) = o;
}

// ---------------------------------------------------------------------------
extern "C" void kernel_launch(void* const* d_in, const int* in_sizes, int n_in,
                              void* d_out, int out_size, void* d_ws, size_t ws_size,
                              hipStream_t stream)
{
    const float* v       = (const float*)d_in[0];
    const float* e       = (const float*)d_in[1];
    const int*   vidx    = (const int*)d_in[2];
    const int*   eidx    = (const int*)d_in[3];
    const float* vrw     = (const float*)d_in[4];
    const float* erw     = (const float*)d_in[5];
    const float* vrs     = (const float*)d_in[6];
    const float* ers     = (const float*)d_in[7];
    const float* Wv2e    = (const float*)d_in[8];
    const float* We2v    = (const float*)d_in[9];
    const float* bv      = (const float*)d_in[10];
    const float* be      = (const float*)d_in[11];
    const float* vweight = (const float*)d_in[12];

    const int N = in_sizes[0] / DD;
    const int E = in_sizes[1] / DD;
    const int M = in_sizes[2];

    float* vout = (float*)d_out;
    float* eout = vout + (size_t)N * DD;

    // workspace layout (ev aliases vw: vw is dead after e_agg)
    char* wsb = (char*)d_ws;
    size_t off = 0;
    auto alloc = [&](size_t bytes) { char* p = wsb + off; off += (bytes + 255) & ~(size_t)255; return p; };
    float* vw      = (float*)alloc((size_t)N * DD * sizeof(float));   // 51.2 MB
    float* ev      = vw;                                              // alias (25.6 MB used)
    int*   e_start = (int*)alloc((size_t)(E + 1) * sizeof(int));
    int*   v_start = (int*)alloc((size_t)(N + 1) * sizeof(int));
    int*   e_cur   = (int*)alloc((size_t)E * sizeof(int));
    int*   v_cur   = (int*)alloc((size_t)N * sizeof(int));
    int*   e_src   = (int*)alloc((size_t)M * sizeof(int));
    float* e_w     = (float*)alloc((size_t)M * sizeof(float));
    int*   v_src   = (int*)alloc((size_t)M * sizeof(int));
    float* v_w     = (float*)alloc((size_t)M * sizeof(float));

    // --- CSR build ---
    hipMemsetAsync(e_cur, 0, (size_t)E * sizeof(int), stream);
    hipMemsetAsync(v_cur, 0, (size_t)N * sizeof(int), stream);
    hist_kernel<<<(M + 255) / 256, 256, 0, stream>>>(eidx, vidx, e_cur, v_cur, M);
    scan_kernel<<<1, 1024, 0, stream>>>(e_cur, e_start, E);
    scan_kernel<<<1, 1024, 0, stream>>>(v_cur, v_start, N);
    hipMemsetAsync(e_cur, 0, (size_t)E * sizeof(int), stream);
    hipMemsetAsync(v_cur, 0, (size_t)N * sizeof(int), stream);
    fill_kernel<<<(M + 255) / 256, 256, 0, stream>>>(eidx, vidx, vrw, erw, e_start, v_start,
                                                     e_cur, v_cur, e_src, e_w, v_src, v_w, M);

    // --- compute ---
    gemm_v2e_kernel<<<(N + TILE_R - 1) / TILE_R, GBLK, 0, stream>>>(v, Wv2e, bv, vweight, vw, N);
    e_agg_kernel<<<(E + 3) / 4, 256, 0, stream>>>(e, vw, e_start, e_src, e_w, ers, eout, E);
    gemm_e2v_kernel<<<(E + TILE_R - 1) / TILE_R, GBLK, 0, stream>>>(eout, We2v, be, ev, E);
    v_agg_kernel<<<(N + 3) / 4, 256, 0, stream>>>(v, ev, v_start, v_src, v_w, vrs, vweight, vout, N);
}

// Round 3
// 549.001 us; speedup vs baseline: 6.3314x; 1.4567x over previous
//
#include <hip/hip_runtime.h>
#include <cstddef>

#define DD 128
#define TILE_R 128
#define GBLK 512
#define AS_LD 132
#define SCAN_CHUNK 2048   // 1024 threads x 2 elements

__device__ __forceinline__ float4 f4add(const float4& a, const float4& b) {
    return make_float4(a.x + b.x, a.y + b.y, a.z + b.z, a.w + b.w);
}
__device__ __forceinline__ float4 f4scale(const float4& a, float s) {
    return make_float4(a.x * s, a.y * s, a.z * s, a.w * s);
}
__device__ __forceinline__ float4 f4relu(const float4& a) {
    return make_float4(fmaxf(a.x, 0.f), fmaxf(a.y, 0.f), fmaxf(a.z, 0.f), fmaxf(a.w, 0.f));
}
__device__ __forceinline__ void f4fma(float a, const float4& b, float4& c) {
    c.x = fmaf(a, b.x, c.x);
    c.y = fmaf(a, b.y, c.y);
    c.z = fmaf(a, b.z, c.z);
    c.w = fmaf(a, b.w, c.w);
}

// ---------------------------------------------------------------------------
// histogram: count incidences per edge and per vertex (one pass over M)
__global__ void hist_kernel(const int* __restrict__ eidx, const int* __restrict__ vidx,
                            int* __restrict__ e_cnt, int* __restrict__ v_cnt, int M)
{
    int m = blockIdx.x * blockDim.x + threadIdx.x;
    if (m >= M) return;
    atomicAdd(&e_cnt[eidx[m]], 1);
    atomicAdd(&v_cnt[vidx[m]], 1);
}

// ---------------------------------------------------------------------------
// multi-block exclusive scan, phase 1: per-block (2048-elem chunk) sums
__global__ __launch_bounds__(1024)
void scan_reduce_kernel(const int* __restrict__ cnt, int* __restrict__ partial, int n)
{
    __shared__ int sdata[1024];
    int base = blockIdx.x * SCAN_CHUNK;
    int t = threadIdx.x;
    int i0 = base + 2 * t;
    int a = (i0 < n)     ? cnt[i0]     : 0;
    int b = (i0 + 1 < n) ? cnt[i0 + 1] : 0;
    sdata[t] = a + b;
    __syncthreads();
    for (int off = 512; off > 0; off >>= 1) {
        if (t < off) sdata[t] += sdata[t + off];
        __syncthreads();
    }
    if (t == 0) partial[blockIdx.x] = sdata[0];
}

// phase 2: exclusive scan of partials (nb <= 1024) in one block; also writes total -> start[n]
__global__ __launch_bounds__(1024)
void scan_partials_kernel(int* __restrict__ partial, int nb, int* __restrict__ start, int n)
{
    __shared__ int sdata[1024];
    int t = threadIdx.x;
    int v = (t < nb) ? partial[t] : 0;
    sdata[t] = v;
    __syncthreads();
    int x = v;
    for (int off = 1; off < 1024; off <<= 1) {
        int y = (t >= off) ? sdata[t - off] : 0;
        __syncthreads();
        x += y;
        sdata[t] = x;
        __syncthreads();
    }
    if (t < nb) partial[t] = x - v;        // exclusive
    if (t == nb - 1) start[n] = x;         // grand total
}

// phase 3: per-chunk scan + chunk base -> exclusive start[]
__global__ __launch_bounds__(1024)
void scan_write_kernel(const int* __restrict__ cnt, const int* __restrict__ partial,
                       int* __restrict__ start, int n)
{
    __shared__ int sdata[1024];
    int base = blockIdx.x * SCAN_CHUNK;
    int t = threadIdx.x;
    int i0 = base + 2 * t;
    int a = (i0 < n)     ? cnt[i0]     : 0;
    int b = (i0 + 1 < n) ? cnt[i0 + 1] : 0;
    int s = a + b;
    sdata[t] = s;
    __syncthreads();
    int x = s;
    for (int off = 1; off < 1024; off <<= 1) {
        int y = (t >= off) ? sdata[t - off] : 0;
        __syncthreads();
        x += y;
        sdata[t] = x;
        __syncthreads();
    }
    int ex = partial[blockIdx.x] + x - s;  // exclusive prefix before element i0
    if (i0 < n)     start[i0]     = ex;
    if (i0 + 1 < n) start[i0 + 1] = ex + a;
}

// ---------------------------------------------------------------------------
// fill packed CSR payloads: (src_row, weight_bits) per incidence, dest-sorted
__global__ void fill_kernel(const int* __restrict__ eidx, const int* __restrict__ vidx,
                            const float* __restrict__ vrw, const float* __restrict__ erw,
                            const int* __restrict__ e_start, const int* __restrict__ v_start,
                            int* __restrict__ e_cur, int* __restrict__ v_cur,
                            int2* __restrict__ e_pack, int2* __restrict__ v_pack, int M)
{
    int m = blockIdx.x * blockDim.x + threadIdx.x;
    if (m >= M) return;
    int ei = eidx[m];
    int vi = vidx[m];
    int p = e_start[ei] + atomicAdd(&e_cur[ei], 1);
    e_pack[p] = make_int2(vi, __float_as_int(vrw[m]));
    int q = v_start[vi] + atomicAdd(&v_cur[vi], 1);
    v_pack[q] = make_int2(ei, __float_as_int(erw[m]));
}

// ---------------------------------------------------------------------------
// GEMM1: vw = relu(v @ W + b_v) * v_weight
__global__ __launch_bounds__(GBLK, 1)
void gemm_v2e_kernel(const float* __restrict__ v, const float* __restrict__ W,
                     const float* __restrict__ bv, const float* __restrict__ vweight,
                     float* __restrict__ vw, int nrows)
{
    __shared__ float Ws[DD * DD];
    __shared__ float As[TILE_R * AS_LD];

    const int t = threadIdx.x;
    const int row0 = blockIdx.x * TILE_R;

    #pragma unroll
    for (int i = 0; i < 8; ++i) {
        int p = t + GBLK * i;
        *reinterpret_cast<float4*>(&Ws[p * 4]) = *reinterpret_cast<const float4*>(&W[p * 4]);
    }
    #pragma unroll
    for (int i = 0; i < 8; ++i) {
        int p  = t + GBLK * i;
        int r  = p >> 5;
        int c4 = p & 31;
        int gr = row0 + r;
        float4 val = make_float4(0.f, 0.f, 0.f, 0.f);
        if (gr < nrows) val = *reinterpret_cast<const float4*>(&v[(size_t)gr * DD + c4 * 4]);
        *reinterpret_cast<float4*>(&As[r * AS_LD + c4 * 4]) = val;
    }
    __syncthreads();

    const int rg = t >> 4;
    const int cg = t & 15;
    const int r0 = rg * 4;
    const int c0 = cg * 4;
    const int c1 = 64 + cg * 4;

    float4 acc0[4], acc1[4];
    #pragma unroll
    for (int i = 0; i < 4; ++i) {
        acc0[i] = make_float4(0.f, 0.f, 0.f, 0.f);
        acc1[i] = make_float4(0.f, 0.f, 0.f, 0.f);
    }

    #pragma unroll 4
    for (int k = 0; k < DD; ++k) {
        float4 b0 = *reinterpret_cast<const float4*>(&Ws[k * DD + c0]);
        float4 b1 = *reinterpret_cast<const float4*>(&Ws[k * DD + c1]);
        #pragma unroll
        for (int i = 0; i < 4; ++i) {
            float a = As[(r0 + i) * AS_LD + k];
            f4fma(a, b0, acc0[i]);
            f4fma(a, b1, acc1[i]);
        }
    }

    float4 bv0 = *reinterpret_cast<const float4*>(&bv[c0]);
    float4 bv1 = *reinterpret_cast<const float4*>(&bv[c1]);

    #pragma unroll
    for (int i = 0; i < 4; ++i) {
        int gr = row0 + r0 + i;
        if (gr >= nrows) break;
        float wt = vweight[gr];
        float4 o0 = f4scale(f4relu(f4add(acc0[i], bv0)), wt);
        float4 o1 = f4scale(f4relu(f4add(acc1[i], bv1)), wt);
        *reinterpret_cast<float4*>(&vw[(size_t)gr * DD + c0]) = o0;
        *reinterpret_cast<float4*>(&vw[(size_t)gr * DD + c1]) = o1;
    }
}

// ---------------------------------------------------------------------------
// GEMM2: ev = relu(e_out @ W + b_e) / 3   (e_out already final)
__global__ __launch_bounds__(GBLK, 1)
void gemm_e2v_kernel(const float* __restrict__ eout, const float* __restrict__ W,
                     const float* __restrict__ be, float* __restrict__ ev, int nrows)
{
    __shared__ float Ws[DD * DD];
    __shared__ float As[TILE_R * AS_LD];

    const int t = threadIdx.x;
    const int row0 = blockIdx.x * TILE_R;

    #pragma unroll
    for (int i = 0; i < 8; ++i) {
        int p = t + GBLK * i;
        *reinterpret_cast<float4*>(&Ws[p * 4]) = *reinterpret_cast<const float4*>(&W[p * 4]);
    }
    #pragma unroll
    for (int i = 0; i < 8; ++i) {
        int p  = t + GBLK * i;
        int r  = p >> 5;
        int c4 = p & 31;
        int gr = row0 + r;
        float4 val = make_float4(0.f, 0.f, 0.f, 0.f);
        if (gr < nrows) val = *reinterpret_cast<const float4*>(&eout[(size_t)gr * DD + c4 * 4]);
        *reinterpret_cast<float4*>(&As[r * AS_LD + c4 * 4]) = val;
    }
    __syncthreads();

    const int rg = t >> 4;
    const int cg = t & 15;
    const int r0 = rg * 4;
    const int c0 = cg * 4;
    const int c1 = 64 + cg * 4;

    float4 acc0[4], acc1[4];
    #pragma unroll
    for (int i = 0; i < 4; ++i) {
        acc0[i] = make_float4(0.f, 0.f, 0.f, 0.f);
        acc1[i] = make_float4(0.f, 0.f, 0.f, 0.f);
    }

    #pragma unroll 4
    for (int k = 0; k < DD; ++k) {
        float4 b0 = *reinterpret_cast<const float4*>(&Ws[k * DD + c0]);
        float4 b1 = *reinterpret_cast<const float4*>(&Ws[k * DD + c1]);
        #pragma unroll
        for (int i = 0; i < 4; ++i) {
            float a = As[(r0 + i) * AS_LD + k];
            f4fma(a, b0, acc0[i]);
            f4fma(a, b1, acc1[i]);
        }
    }

    float4 be0 = *reinterpret_cast<const float4*>(&be[c0]);
    float4 be1 = *reinterpret_cast<const float4*>(&be[c1]);
    const float third = 1.0f / 3.0f;

    #pragma unroll
    for (int i = 0; i < 4; ++i) {
        int gr = row0 + r0 + i;
        if (gr >= nrows) break;
        float4 o0 = f4scale(f4relu(f4add(acc0[i], be0)), third);
        float4 o1 = f4scale(f4relu(f4add(acc1[i], be1)), third);
        *reinterpret_cast<float4*>(&ev[(size_t)gr * DD + c0]) = o0;
        *reinterpret_cast<float4*>(&ev[(size_t)gr * DD + c1]) = o1;
    }
}

// ---------------------------------------------------------------------------
// e-aggregation: eout[row] = (e[row] + sum_j w_j * vw[src_j]) / ers[row]
// one wave (64 lanes, float2 each) per edge; 4 edges per 256-thread block
__global__ __launch_bounds__(256)
void e_agg_kernel(const float* __restrict__ e, const float* __restrict__ vw,
                  const int* __restrict__ start, const int2* __restrict__ pack,
                  const float* __restrict__ ers, float* __restrict__ eout, int E)
{
    int row = blockIdx.x * 4 + (threadIdx.x >> 6);
    if (row >= E) return;
    int lane = threadIdx.x & 63;
    int s = start[row], t = start[row + 1];
    float2 acc = make_float2(0.f, 0.f);
    for (int j = s; j < t; ++j) {
        int2 pw = pack[j];
        float wm = __int_as_float(pw.y);
        float2 x = *reinterpret_cast<const float2*>(&vw[(size_t)pw.x * DD + lane * 2]);
        acc.x = fmaf(x.x, wm, acc.x);
        acc.y = fmaf(x.y, wm, acc.y);
    }
    float rs = 1.0f / ers[row];
    float2 er = *reinterpret_cast<const float2*>(&e[(size_t)row * DD + lane * 2]);
    float2 o = make_float2((er.x + acc.x) * rs, (er.y + acc.y) * rs);
    *reinterpret_cast<float2*>(&eout[(size_t)row * DD + lane * 2]) = o;
}

// ---------------------------------------------------------------------------
// v-aggregation: vout[row] = (v[row]*vweight[row]*4 + sum_j w_j * ev[src_j]) / vrs[row]
__global__ __launch_bounds__(256)
void v_agg_kernel(const float* __restrict__ v, const float* __restrict__ ev,
                  const int* __restrict__ start, const int2* __restrict__ pack,
                  const float* __restrict__ vrs, const float* __restrict__ vweight,
                  float* __restrict__ vout, int N)
{
    int row = blockIdx.x * 4 + (threadIdx.x >> 6);
    if (row >= N) return;
    int lane = threadIdx.x & 63;
    int s = start[row], t = start[row + 1];
    float2 acc = make_float2(0.f, 0.f);
    for (int j = s; j < t; ++j) {
        int2 pw = pack[j];
        float wm = __int_as_float(pw.y);
        float2 x = *reinterpret_cast<const float2*>(&ev[(size_t)pw.x * DD + lane * 2]);
        acc.x = fmaf(x.x, wm, acc.x);
        acc.y = fmaf(x.y, wm, acc.y);
    }
    float rs = 1.0f / vrs[row];
    float wt = vweight[row] * 4.0f;
    float2 vr = *reinterpret_cast<const float2*>(&v[(size_t)row * DD + lane * 2]);
    float2 o = make_float2((vr.x * wt + acc.x) * rs, (vr.y * wt + acc.y) * rs);
    *reinterpret_cast<float2*>(&vout[(size_t)row * DD + lane * 2]) = o;
}

// ---------------------------------------------------------------------------
extern "C" void kernel_launch(void* const* d_in, const int* in_sizes, int n_in,
                              void* d_out, int out_size, void* d_ws, size_t ws_size,
                              hipStream_t stream)
{
    const float* v       = (const float*)d_in[0];
    const float* e       = (const float*)d_in[1];
    const int*   vidx    = (const int*)d_in[2];
    const int*   eidx    = (const int*)d_in[3];
    const float* vrw     = (const float*)d_in[4];
    const float* erw     = (const float*)d_in[5];
    const float* vrs     = (const float*)d_in[6];
    const float* ers     = (const float*)d_in[7];
    const float* Wv2e    = (const float*)d_in[8];
    const float* We2v    = (const float*)d_in[9];
    const float* bv      = (const float*)d_in[10];
    const float* be      = (const float*)d_in[11];
    const float* vweight = (const float*)d_in[12];

    const int N = in_sizes[0] / DD;
    const int E = in_sizes[1] / DD;
    const int M = in_sizes[2];

    float* vout = (float*)d_out;
    float* eout = vout + (size_t)N * DD;

    // workspace layout (ev aliases vw: vw is dead after e_agg)
    char* wsb = (char*)d_ws;
    size_t off = 0;
    auto alloc = [&](size_t bytes) { char* p = wsb + off; off += (bytes + 255) & ~(size_t)255; return p; };
    float* vw      = (float*)alloc((size_t)N * DD * sizeof(float));   // 51.2 MB
    float* ev      = vw;                                              // alias (25.6 MB used)
    int*   e_start = (int*)alloc((size_t)(E + 1) * sizeof(int));
    int*   v_start = (int*)alloc((size_t)(N + 1) * sizeof(int));
    int*   e_cur   = (int*)alloc((size_t)E * sizeof(int));
    int*   v_cur   = (int*)alloc((size_t)N * sizeof(int));
    int*   e_part  = (int*)alloc(1024 * sizeof(int));
    int*   v_part  = (int*)alloc(1024 * sizeof(int));
    int2*  e_pack  = (int2*)alloc((size_t)M * sizeof(int2));
    int2*  v_pack  = (int2*)alloc((size_t)M * sizeof(int2));

    const int e_nb = (E + SCAN_CHUNK - 1) / SCAN_CHUNK;
    const int v_nb = (N + SCAN_CHUNK - 1) / SCAN_CHUNK;

    // --- CSR build ---
    hipMemsetAsync(e_cur, 0, (size_t)E * sizeof(int), stream);
    hipMemsetAsync(v_cur, 0, (size_t)N * sizeof(int), stream);
    hist_kernel<<<(M + 255) / 256, 256, 0, stream>>>(eidx, vidx, e_cur, v_cur, M);
    scan_reduce_kernel<<<e_nb, 1024, 0, stream>>>(e_cur, e_part, E);
    scan_partials_kernel<<<1, 1024, 0, stream>>>(e_part, e_nb, e_start, E);
    scan_write_kernel<<<e_nb, 1024, 0, stream>>>(e_cur, e_part, e_start, E);
    scan_reduce_kernel<<<v_nb, 1024, 0, stream>>>(v_cur, v_part, N);
    scan_partials_kernel<<<1, 1024, 0, stream>>>(v_part, v_nb, v_start, N);
    scan_write_kernel<<<v_nb, 1024, 0, stream>>>(v_cur, v_part, v_start, N);
    hipMemsetAsync(e_cur, 0, (size_t)E * sizeof(int), stream);
    hipMemsetAsync(v_cur, 0, (size_t)N * sizeof(int), stream);
    fill_kernel<<<(M + 255) / 256, 256, 0, stream>>>(eidx, vidx, vrw, erw, e_start, v_start,
                                                     e_cur, v_cur, e_pack, v_pack, M);

    // --- compute ---
    gemm_v2e_kernel<<<(N + TILE_R - 1) / TILE_R, GBLK, 0, stream>>>(v, Wv2e, bv, vweight, vw, N);
    e_agg_kernel<<<(E + 3) / 4, 256, 0, stream>>>(e, vw, e_start, e_pack, ers, eout, E);
    gemm_e2v_kernel<<<(E + TILE_R - 1) / TILE_R, GBLK, 0, stream>>>(eout, We2v, be, ev, E);
    v_agg_kernel<<<(N + 3) / 4, 256, 0, stream>>>(v, ev, v_start, v_pack, vrs, vweight, vout, N);
}